// Round 5
// baseline (292.852 us; speedup 1.0000x reference)
//
#include <hip/hip_runtime.h>
#include <hip/hip_bf16.h>

#define BBATCH 8
#define TSEQ   1024
#define DMODEL 1024
#define NHEAD  16
#define HSZ    64

typedef unsigned short ushort_t;
typedef __attribute__((ext_vector_type(8))) short short8;
typedef __attribute__((ext_vector_type(4))) float float4v;

__device__ __forceinline__ ushort_t f2bf(float f) {
    __hip_bfloat16 h = __float2bfloat16(f);
    return *reinterpret_cast<ushort_t*>(&h);
}
// fast fp32->bf16, round-half-up
__device__ __forceinline__ ushort_t f2bf_fast(float f) {
    return (ushort_t)((__float_as_uint(f) + 0x8000u) >> 16);
}
// pack two fp32 -> uint {bf16(lo), bf16(hi)}
__device__ __forceinline__ unsigned int pack_bf2(float lo, float hi) {
    unsigned int a = __float_as_uint(lo) + 0x8000u;
    unsigned int b = __float_as_uint(hi) + 0x8000u;
    return __builtin_amdgcn_perm(b, a, 0x07060302u);
}

__device__ __forceinline__ short8 cvt8(const float* f) {
    union { ushort_t u[8]; short8 v; } r;
    #pragma unroll
    for (int e = 0; e < 8; ++e) r.u[e] = f2bf(f[e]);
    return r.v;
}

// async global->LDS, 16B/lane; lds base wave-uniform (HW: base + lane*16)
__device__ __forceinline__ void async16(const ushort_t* g, ushort_t* l) {
    __builtin_amdgcn_global_load_lds(
        (const __attribute__((address_space(1))) unsigned int*)g,
        (__attribute__((address_space(3))) unsigned int*)l, 16, 0, 0);
}

// ---------------------------------------------------------------------------
// cvt_x: X fp32 [8192x1024] -> bf16 (lives in d_out scratch). 16 elems/thread.
// ---------------------------------------------------------------------------
__global__ __launch_bounds__(256) void cvt_x(
    const float* __restrict__ X, ushort_t* __restrict__ Xb)
{
    const size_t idx = ((size_t)blockIdx.x * 256 + threadIdx.x) * 16;
    float f[16];
    *(float4*)(f + 0)  = *(const float4*)(X + idx);
    *(float4*)(f + 4)  = *(const float4*)(X + idx + 4);
    *(float4*)(f + 8)  = *(const float4*)(X + idx + 8);
    *(float4*)(f + 12) = *(const float4*)(X + idx + 12);
    uint4 o0 = make_uint4(pack_bf2(f[0], f[1]),  pack_bf2(f[2], f[3]),
                          pack_bf2(f[4], f[5]),  pack_bf2(f[6], f[7]));
    uint4 o1 = make_uint4(pack_bf2(f[8], f[9]),  pack_bf2(f[10], f[11]),
                          pack_bf2(f[12], f[13]), pack_bf2(f[14], f[15]));
    *(uint4*)(Xb + idx) = o0;
    *(uint4*)(Xb + idx + 8) = o1;
}

// ---------------------------------------------------------------------------
// pack_w: WpackT[w*1024 + h*64 + s][d] = W_w[h][d][s]  (fp32 -> bf16, n-major)
// ---------------------------------------------------------------------------
__global__ __launch_bounds__(256) void pack_w(
    const float* __restrict__ Wq, const float* __restrict__ Wk,
    const float* __restrict__ Wv, ushort_t* __restrict__ WpT)
{
    __shared__ ushort_t L[64 * 72];
    const int tid = threadIdx.x;
    const int d0 = blockIdx.x * 64;
    const int wh = blockIdx.y;
    const int w = wh >> 4, h = wh & 15;
    const float* W = (w == 0 ? Wq : (w == 1 ? Wk : Wv)) + (size_t)h * DMODEL * HSZ;

    int dr = tid >> 2, sc = (tid & 3) * 16;
    const float4* src = (const float4*)(W + (size_t)(d0 + dr) * HSZ + sc);
    float f[16];
    *(float4*)(f + 0) = src[0]; *(float4*)(f + 4) = src[1];
    *(float4*)(f + 8) = src[2]; *(float4*)(f + 12) = src[3];
    *(short8*)(L + dr * 72 + sc)     = cvt8(f);
    *(short8*)(L + dr * 72 + sc + 8) = cvt8(f + 8);
    __syncthreads();

    int s = tid >> 2, dc = (tid & 3) * 16;
    union { ushort_t u[16]; short8 v[2]; } o;
    #pragma unroll
    for (int j = 0; j < 16; ++j) o.u[j] = L[(dc + j) * 72 + s];
    ushort_t* dst = WpT + (size_t)(w * 1024 + h * 64 + s) * DMODEL + d0 + dc;
    *(short8*)dst = o.v[0];
    *(short8*)(dst + 8) = o.v[1];
}

// ---------------------------------------------------------------------------
// transpose_v: Vt[bh][s][t] = Vb[bh][t][s]   (bf16)
// ---------------------------------------------------------------------------
__global__ __launch_bounds__(256) void transpose_v(
    const ushort_t* __restrict__ Vb, ushort_t* __restrict__ Vt)
{
    __shared__ ushort_t L[64 * 72];
    const int tid = threadIdx.x;
    const int t0 = blockIdx.x * 64;
    const int bh = blockIdx.y;
    const size_t base = (size_t)bh * TSEQ * HSZ;

    int r = tid >> 2, c16 = (tid & 3) * 16;
    const ushort_t* src = Vb + base + (size_t)(t0 + r) * HSZ + c16;
    *(short8*)(L + r * 72 + c16)     = *(const short8*)src;
    *(short8*)(L + r * 72 + c16 + 8) = *(const short8*)(src + 8);
    __syncthreads();

    int s = tid >> 2, tc = (tid & 3) * 16;
    union { ushort_t u[16]; short8 v[2]; } o;
    #pragma unroll
    for (int j = 0; j < 16; ++j) o.u[j] = L[(tc + j) * 72 + s];
    ushort_t* dst = Vt + base + (size_t)s * TSEQ + t0 + tc;
    *(short8*)dst = o.v[0];
    *(short8*)(dst + 8) = o.v[1];
}

// ---------------------------------------------------------------------------
// qkv_gemm: C[m][n] = sum_d Xb[m][d] * WpT[n][d]. Block 128x256, wave 64x128
// (acc 4x8), BK=32. Both A and B staged via global_load_lds, double-buffered,
// one barrier per iter; DMA(j+1) issued before compute(j) so the pre-barrier
// vmcnt(0) drain lands after a full compute phase. 4-chunk XOR swizzle
// ch = q ^ (r&3) ^ ((r>>2)&3) -> <=2-way LDS access (free).
// Q pre-scaled by 0.125*log2(e). grid (12, 64).
// ---------------------------------------------------------------------------
#define QBM 128
#define QBN 256
#define QBK 32

__global__ __launch_bounds__(256, 2) void qkv_gemm(
    const ushort_t* __restrict__ Xb, const ushort_t* __restrict__ WpT,
    ushort_t* __restrict__ Qb, ushort_t* __restrict__ Kb, ushort_t* __restrict__ Vb)
{
    __shared__ ushort_t As[2][QBM * QBK];
    __shared__ ushort_t Bs[2][QBN * QBK];
    const int tid = threadIdx.x;
    const int wave = tid >> 6, lane = tid & 63;
    const int q = lane >> 4, cc = lane & 15;
    const int n0 = blockIdx.x * QBN, m0 = blockIdx.y * QBM;
    const int wm = wave >> 1, wn = wave & 1;

    // A DMA: 2 instrs/wave, 16 rows each
    const ushort_t* ag[2]; int alo[2];
    #pragma unroll
    for (int i = 0; i < 2; ++i) {
        int rbase = wave * 32 + i * 16;
        int r = rbase + (lane >> 2);
        int lc = (lane & 3) ^ ((r & 3) ^ ((r >> 2) & 3));
        ag[i] = Xb + (size_t)(m0 + r) * DMODEL + lc * 8;
        alo[i] = rbase * QBK;
    }
    // B DMA: 4 instrs/wave
    const ushort_t* bg[4]; int blo[4];
    #pragma unroll
    for (int i = 0; i < 4; ++i) {
        int rbase = wave * 64 + i * 16;
        int r = rbase + (lane >> 2);
        int lc = (lane & 3) ^ ((r & 3) ^ ((r >> 2) & 3));
        bg[i] = WpT + (size_t)(n0 + r) * DMODEL + lc * 8;
        blo[i] = rbase * QBK;
    }
    // fragment offsets
    int aoff[4], boff[8];
    #pragma unroll
    for (int mt = 0; mt < 4; ++mt) {
        int r = wm * 64 + mt * 16 + cc;
        aoff[mt] = r * QBK + ((q ^ (r & 3) ^ ((r >> 2) & 3)) * 8);
    }
    #pragma unroll
    for (int nt = 0; nt < 8; ++nt) {
        int r = wn * 128 + nt * 16 + cc;
        boff[nt] = r * QBK + ((q ^ (r & 3) ^ ((r >> 2) & 3)) * 8);
    }

    float4v acc[4][8];
    #pragma unroll
    for (int a = 0; a < 4; ++a)
        #pragma unroll
        for (int b = 0; b < 8; ++b) acc[a][b] = (float4v){0.f, 0.f, 0.f, 0.f};

    // prologue: chunk 0 -> buffer 0
    #pragma unroll
    for (int i = 0; i < 2; ++i) async16(ag[i], &As[0][alo[i]]);
    #pragma unroll
    for (int i = 0; i < 4; ++i) async16(bg[i], &Bs[0][blo[i]]);
    __syncthreads();

    for (int j = 0; j < 32; ++j) {
        const ushort_t* asc = As[j & 1];
        const ushort_t* bsc = Bs[j & 1];
        if (j < 31) {
            int nb = (j + 1) & 1;
            #pragma unroll
            for (int i = 0; i < 2; ++i) {
                ag[i] += QBK;
                async16(ag[i], &As[nb][alo[i]]);
            }
            #pragma unroll
            for (int i = 0; i < 4; ++i) {
                bg[i] += QBK;
                async16(bg[i], &Bs[nb][blo[i]]);
            }
        }

        short8 av[4], bv[8];
        #pragma unroll
        for (int mt = 0; mt < 4; ++mt) av[mt] = *(const short8*)(asc + aoff[mt]);
        #pragma unroll
        for (int nt = 0; nt < 8; ++nt) bv[nt] = *(const short8*)(bsc + boff[nt]);
        #pragma unroll
        for (int mt = 0; mt < 4; ++mt)
            #pragma unroll
            for (int nt = 0; nt < 8; ++nt)
                acc[mt][nt] = __builtin_amdgcn_mfma_f32_16x16x32_bf16(
                    av[mt], bv[nt], acc[mt][nt], 0, 0, 0);
        __syncthreads();   // drains DMA(j+1): full compute phase elapsed
    }

    // epilogue: scatter to Q/K/V [B,H,T,HS]; wsel uniform per block (256|1024)
    const int nbase0 = n0 + wn * 128;
    const int wsel = nbase0 >> 10;
    ushort_t* Out = wsel == 0 ? Qb : (wsel == 1 ? Kb : Vb);
    const float osc = (wsel == 0) ? 0.18033688011112042f : 1.0f; // 0.125*log2(e)
    #pragma unroll
    for (int mt = 0; mt < 4; ++mt)
        #pragma unroll
        for (int rr = 0; rr < 4; ++rr) {
            int m = m0 + wm * 64 + mt * 16 + q * 4 + rr;
            int b = m >> 10, t = m & 1023;
            #pragma unroll
            for (int nt = 0; nt < 8; ++nt) {
                int n = nbase0 + nt * 16;
                int h = (n >> 6) & 15;
                size_t rb = (((size_t)(b * NHEAD + h)) * TSEQ + t) * HSZ + (n & 63) + cc;
                Out[rb] = f2bf_fast(acc[mt][nt][rr] * osc);
            }
        }
}

// ---------------------------------------------------------------------------
// attn: flash attention, Q-tile 128, KV-tile 64, double-buffered DMA prefetch.
// S^T = K·Q^T; exp2-domain softmax without running max. grid (8,128).
// ---------------------------------------------------------------------------
__global__ __launch_bounds__(256) void attn(
    const ushort_t* __restrict__ Qb, const ushort_t* __restrict__ Kb,
    const ushort_t* __restrict__ Vt, ushort_t* __restrict__ Ob)
{
    __shared__ ushort_t Ks[2][64 * 64];
    __shared__ ushort_t VTs[2][64 * 64];
    __shared__ ushort_t Ps[4][32 * 72];
    const int tid = threadIdx.x;
    const int wave = tid >> 6, lane = tid & 63;
    const int q = lane >> 4, cc = lane & 15;
    const int qt = 7 - (int)blockIdx.x;
    const int bh = blockIdx.y;
    const size_t base = (size_t)bh * TSEQ * HSZ;
    const int J = 2 * qt + 2;

    const ushort_t* kg[2]; const ushort_t* vg[2]; int dmo[2];
    #pragma unroll
    for (int i = 0; i < 2; ++i) {
        int rr = wave * 16 + i * 8 + (lane >> 3);
        int ch = (lane & 7) ^ (rr & 7);
        kg[i] = Kb + base + (size_t)rr * HSZ + ch * 8;
        vg[i] = Vt + base + (size_t)rr * TSEQ + ch * 8;
        dmo[i] = (wave * 16 + i * 8) * 64;
    }

    short8 qf[2][2];
    #pragma unroll
    for (int tt = 0; tt < 2; ++tt) {
        const ushort_t* qp = Qb + base +
            (size_t)(qt * 128 + wave * 32 + tt * 16 + cc) * HSZ + q * 8;
        qf[tt][0] = *(const short8*)qp;
        qf[tt][1] = *(const short8*)(qp + 32);
    }

    int koff[4][2], poff[2][2];
    #pragma unroll
    for (int ut = 0; ut < 4; ++ut)
        #pragma unroll
        for (int kt = 0; kt < 2; ++kt)
            koff[ut][kt] = (ut * 16 + cc) * 64 + (((kt * 4 + q) ^ (cc & 7)) * 8);
    #pragma unroll
    for (int tt = 0; tt < 2; ++tt)
        #pragma unroll
        for (int kt = 0; kt < 2; ++kt)
            poff[tt][kt] = (tt * 16 + cc) * 72 + kt * 32 + q * 8;

    float4v oacc[2][4];
    #pragma unroll
    for (int tt = 0; tt < 2; ++tt)
        #pragma unroll
        for (int st = 0; st < 4; ++st) oacc[tt][st] = (float4v){0.f, 0.f, 0.f, 0.f};
    float lsum[2] = {0.f, 0.f};

    #pragma unroll
    for (int i = 0; i < 2; ++i) {
        async16(kg[i], &Ks[0][dmo[i]]);
        async16(vg[i], &VTs[0][dmo[i]]);
    }
    __syncthreads();

    for (int jt = 0; jt < J; ++jt) {
        const ushort_t* Kc = Ks[jt & 1];
        const ushort_t* Vc = VTs[jt & 1];
        if (jt + 1 < J) {
            int nb = (jt + 1) & 1;
            #pragma unroll
            for (int i = 0; i < 2; ++i) {
                async16(kg[i] + (size_t)(jt + 1) * 64 * HSZ, &Ks[nb][dmo[i]]);
                async16(vg[i] + (jt + 1) * 64, &VTs[nb][dmo[i]]);
            }
        }

        float4v sc[4][2];
        #pragma unroll
        for (int ut = 0; ut < 4; ++ut)
            #pragma unroll
            for (int tt = 0; tt < 2; ++tt) sc[ut][tt] = (float4v){0.f, 0.f, 0.f, 0.f};
        #pragma unroll
        for (int kt = 0; kt < 2; ++kt) {
            short8 kf[4];
            #pragma unroll
            for (int ut = 0; ut < 4; ++ut) kf[ut] = *(const short8*)(Kc + koff[ut][kt]);
            #pragma unroll
            for (int ut = 0; ut < 4; ++ut) {
                sc[ut][0] = __builtin_amdgcn_mfma_f32_16x16x32_bf16(
                    kf[ut], qf[0][kt], sc[ut][0], 0, 0, 0);
                sc[ut][1] = __builtin_amdgcn_mfma_f32_16x16x32_bf16(
                    kf[ut], qf[1][kt], sc[ut][1], 0, 0, 0);
            }
        }

        const bool diag = ((jt >> 1) == qt);
        #pragma unroll
        for (int tt = 0; tt < 2; ++tt) {
            const int tg = qt * 128 + wave * 32 + tt * 16 + cc;
            #pragma unroll
            for (int ut = 0; ut < 4; ++ut) {
                float pv[4]; float ps = 0.f;
                #pragma unroll
                for (int rr = 0; rr < 4; ++rr) {
                    float p = exp2f(sc[ut][tt][rr]);
                    if (diag && (jt * 64 + ut * 16 + q * 4 + rr) > tg) p = 0.f;
                    pv[rr] = p; ps += p;
                }
                lsum[tt] += ps;
                *(uint2*)&Ps[wave][(tt * 16 + cc) * 72 + ut * 16 + q * 4] =
                    make_uint2(pack_bf2(pv[0], pv[1]), pack_bf2(pv[2], pv[3]));
            }
        }

        #pragma unroll
        for (int kt = 0; kt < 2; ++kt) {
            short8 pa0 = *(const short8*)&Ps[wave][poff[0][kt]];
            short8 pa1 = *(const short8*)&Ps[wave][poff[1][kt]];
            #pragma unroll
            for (int st = 0; st < 4; ++st) {
                short8 vf = *(const short8*)(Vc + koff[st][kt]);
                oacc[0][st] = __builtin_amdgcn_mfma_f32_16x16x32_bf16(
                    pa0, vf, oacc[0][st], 0, 0, 0);
                oacc[1][st] = __builtin_amdgcn_mfma_f32_16x16x32_bf16(
                    pa1, vf, oacc[1][st], 0, 0, 0);
            }
        }
        __syncthreads();
    }

    float inv[2];
    #pragma unroll
    for (int tt = 0; tt < 2; ++tt) {
        float l = lsum[tt];
        l += __shfl_xor(l, 16);
        l += __shfl_xor(l, 32);
        inv[tt] = 1.f / l;
    }
    const int b = bh >> 4, h = bh & 15;
    #pragma unroll
    for (int tt = 0; tt < 2; ++tt)
        #pragma unroll
        for (int rr = 0; rr < 4; ++rr) {
            float iv = __shfl(inv[tt], q * 4 + rr);
            int t = qt * 128 + wave * 32 + tt * 16 + q * 4 + rr;
            size_t rb = ((size_t)b * TSEQ + t) * DMODEL + h * HSZ;
            #pragma unroll
            for (int st = 0; st < 4; ++st)
                Ob[rb + st * 16 + cc] = f2bf_fast(oacc[tt][st][rr] * iv);
        }
}

// ---------------------------------------------------------------------------
// oproj_gemm: out[m][n] = sum_k Ob[m][k]*Wo[n][k] + bo[n]. A DMA dbuf;
// B (Wo fp32) perm-staged. grid (8, 64).
// ---------------------------------------------------------------------------
__global__ __launch_bounds__(256, 3) void oproj_gemm(
    const ushort_t* __restrict__ Obuf, const float* __restrict__ Wo,
    const float* __restrict__ bo, float* __restrict__ out)
{
    __shared__ ushort_t As[2][128 * 64];
    __shared__ ushort_t Bs[128 * 64];
    const int tid = threadIdx.x;
    const int wave = tid >> 6, lane = tid & 63;
    const int q = lane >> 4, cc = lane & 15;
    const int n0 = blockIdx.x * 128, m0 = blockIdx.y * 128;
    const int wm = wave >> 1, wn = wave & 1;

    const int sr = tid >> 3, scc = tid & 7;
    const float* bp[4]; ushort_t* bw[4];
    #pragma unroll
    for (int p = 0; p < 4; ++p) {
        int r = p * 32 + sr;
        bp[p] = Wo + (size_t)(n0 + r) * DMODEL + scc * 8;
        bw[p] = Bs + r * 64 + ((scc ^ (r & 7)) * 8);
    }
    const ushort_t* ag[4]; int ao_[4];
    #pragma unroll
    for (int j = 0; j < 4; ++j) {
        int row = wave * 32 + j * 8 + (lane >> 3);
        int ch = (lane & 7) ^ (row & 7);
        ag[j] = Obuf + (size_t)(m0 + row) * DMODEL + ch * 8;
        ao_[j] = (wave * 32 + j * 8) * 64;
    }
    int aoff[4][2]; const ushort_t* bfp[4][2];
    #pragma unroll
    for (int mt = 0; mt < 4; ++mt) {
        int row = wm * 64 + mt * 16 + cc;
        #pragma unroll
        for (int kt = 0; kt < 2; ++kt)
            aoff[mt][kt] = row * 64 + (((kt * 4 + q) ^ (row & 7)) * 8);
    }
    #pragma unroll
    for (int nt = 0; nt < 4; ++nt) {
        int row = wn * 64 + nt * 16 + cc;
        #pragma unroll
        for (int kt = 0; kt < 2; ++kt)
            bfp[nt][kt] = Bs + row * 64 + (((kt * 4 + q) ^ (row & 7)) * 8);
    }

    float4v acc[4][4];
    #pragma unroll
    for (int a = 0; a < 4; ++a)
        #pragma unroll
        for (int b = 0; b < 4; ++b) acc[a][b] = (float4v){0.f, 0.f, 0.f, 0.f};

    #pragma unroll
    for (int j = 0; j < 4; ++j) async16(ag[j], &As[0][ao_[j]]);
    #pragma unroll
    for (int p = 0; p < 4; ++p) {
        float f[8];
        *(float4*)(f)     = *(const float4*)(bp[p]);
        *(float4*)(f + 4) = *(const float4*)(bp[p] + 4);
        *(uint4*)bw[p] = make_uint4(pack_bf2(f[0], f[1]), pack_bf2(f[2], f[3]),
                                    pack_bf2(f[4], f[5]), pack_bf2(f[6], f[7]));
    }
    __syncthreads();

    float pre[4][8];
    for (int j = 0; j < 16; ++j) {
        const ushort_t* asc = As[j & 1];
        if (j < 15) {
            #pragma unroll
            for (int jj = 0; jj < 4; ++jj) {
                ag[jj] += 64;
                async16(ag[jj], &As[(j + 1) & 1][ao_[jj]]);
            }
            #pragma unroll
            for (int p = 0; p < 4; ++p) {
                bp[p] += 64;
                *(float4*)(pre[p])     = *(const float4*)(bp[p]);
                *(float4*)(pre[p] + 4) = *(const float4*)(bp[p] + 4);
            }
        }

        short8 av[4][2], bv[4][2];
        #pragma unroll
        for (int mt = 0; mt < 4; ++mt) {
            av[mt][0] = *(const short8*)(asc + aoff[mt][0]);
            av[mt][1] = *(const short8*)(asc + aoff[mt][1]);
        }
        #pragma unroll
        for (int nt = 0; nt < 4; ++nt) {
            bv[nt][0] = *(const short8*)bfp[nt][0];
            bv[nt][1] = *(const short8*)bfp[nt][1];
        }
        #pragma unroll
        for (int kt = 0; kt < 2; ++kt)
            #pragma unroll
            for (int mt = 0; mt < 4; ++mt)
                #pragma unroll
                for (int nt = 0; nt < 4; ++nt)
                    acc[mt][nt] = __builtin_amdgcn_mfma_f32_16x16x32_bf16(
                        av[mt][kt], bv[nt][kt], acc[mt][nt], 0, 0, 0);
        __syncthreads();

        if (j < 15) {
            #pragma unroll
            for (int p = 0; p < 4; ++p)
                *(uint4*)bw[p] = make_uint4(
                    pack_bf2(pre[p][0], pre[p][1]), pack_bf2(pre[p][2], pre[p][3]),
                    pack_bf2(pre[p][4], pre[p][5]), pack_bf2(pre[p][6], pre[p][7]));
        }
        __syncthreads();
    }

    #pragma unroll
    for (int nt = 0; nt < 4; ++nt) {
        int n = n0 + wn * 64 + nt * 16 + cc;
        float bias = bo[n];
        #pragma unroll
        for (int mt = 0; mt < 4; ++mt)
            #pragma unroll
            for (int rr = 0; rr < 4; ++rr) {
                int m = m0 + wm * 64 + mt * 16 + q * 4 + rr;
                out[(size_t)m * DMODEL + n] = acc[mt][nt][rr] + bias;
            }
    }
}

// ---------------------------------------------------------------------------
extern "C" void kernel_launch(void* const* d_in, const int* in_sizes, int n_in,
                              void* d_out, int out_size, void* d_ws, size_t ws_size,
                              hipStream_t stream)
{
    const float* x  = (const float*)d_in[0];
    const float* Wq = (const float*)d_in[1];
    const float* Wk = (const float*)d_in[2];
    const float* Wv = (const float*)d_in[3];
    const float* Wo = (const float*)d_in[4];
    const float* bo = (const float*)d_in[5];
    float* out = (float*)d_out;

    // ws (64MB): [0,16M) Qb  [16,32) Kb  [32,48) Vb->Ob  [48,64) WpT->Vt
    // Xb (bf16 X, 16MB) lives in d_out's first half: dead before oproj writes.
    const size_t SEG = (size_t)8 * 1024 * 1024;
    ushort_t* Qb  = (ushort_t*)d_ws;
    ushort_t* Kb  = Qb + SEG;
    ushort_t* Vb  = Kb + SEG;
    ushort_t* Ob  = Vb;          // Vb dead after transpose_v
    ushort_t* WpT = Vb + SEG;
    ushort_t* Vtb = WpT;         // WpT dead after qkv_gemm
    ushort_t* Xb  = (ushort_t*)d_out;

    cvt_x      <<<dim3(2048),    256, 0, stream>>>(x, Xb);
    pack_w     <<<dim3(16, 48),  256, 0, stream>>>(Wq, Wk, Wv, WpT);
    qkv_gemm   <<<dim3(12, 64),  256, 0, stream>>>(Xb, WpT, Qb, Kb, Vb);
    transpose_v<<<dim3(16, 128), 256, 0, stream>>>(Vb, Vtb);
    attn       <<<dim3(8, 128),  256, 0, stream>>>(Qb, Kb, Vtb, Ob);
    oproj_gemm <<<dim3(8, 64),   256, 0, stream>>>(Ob, Wo, bo, out);
}

// Round 6
// 247.400 us; speedup vs baseline: 1.1837x; 1.1837x over previous
//
#include <hip/hip_runtime.h>
#include <hip/hip_bf16.h>

#define BBATCH 8
#define TSEQ   1024
#define DMODEL 1024
#define NHEAD  16
#define HSZ    64

typedef unsigned short ushort_t;
typedef __attribute__((ext_vector_type(8))) short short8;
typedef __attribute__((ext_vector_type(4))) float float4v;

__device__ __forceinline__ ushort_t f2bf(float f) {
    __hip_bfloat16 h = __float2bfloat16(f);
    return *reinterpret_cast<ushort_t*>(&h);
}
// fast fp32->bf16, round-half-up
__device__ __forceinline__ ushort_t f2bf_fast(float f) {
    return (ushort_t)((__float_as_uint(f) + 0x8000u) >> 16);
}
// pack two fp32 -> uint {bf16(lo), bf16(hi)}
__device__ __forceinline__ unsigned int pack_bf2(float lo, float hi) {
    unsigned int a = __float_as_uint(lo) + 0x8000u;
    unsigned int b = __float_as_uint(hi) + 0x8000u;
    return __builtin_amdgcn_perm(b, a, 0x07060302u);
}

__device__ __forceinline__ short8 cvt8(const float* f) {
    union { ushort_t u[8]; short8 v; } r;
    #pragma unroll
    for (int e = 0; e < 8; ++e) r.u[e] = f2bf(f[e]);
    return r.v;
}

// async global->LDS, 16B/lane; lds base wave-uniform (HW: base + lane*16)
__device__ __forceinline__ void async16(const ushort_t* g, ushort_t* l) {
    __builtin_amdgcn_global_load_lds(
        (const __attribute__((address_space(1))) unsigned int*)g,
        (__attribute__((address_space(3))) unsigned int*)l, 16, 0, 0);
}

// ---------------------------------------------------------------------------
// cvt_f32_bf16: generic fp32 -> bf16, 16 elems/thread (used for X and Wo)
// ---------------------------------------------------------------------------
__global__ __launch_bounds__(256) void cvt_f32_bf16(
    const float* __restrict__ src, ushort_t* __restrict__ dst)
{
    const size_t idx = ((size_t)blockIdx.x * 256 + threadIdx.x) * 16;
    float f[16];
    *(float4*)(f + 0)  = *(const float4*)(src + idx);
    *(float4*)(f + 4)  = *(const float4*)(src + idx + 4);
    *(float4*)(f + 8)  = *(const float4*)(src + idx + 8);
    *(float4*)(f + 12) = *(const float4*)(src + idx + 12);
    uint4 o0 = make_uint4(pack_bf2(f[0], f[1]),   pack_bf2(f[2], f[3]),
                          pack_bf2(f[4], f[5]),   pack_bf2(f[6], f[7]));
    uint4 o1 = make_uint4(pack_bf2(f[8], f[9]),   pack_bf2(f[10], f[11]),
                          pack_bf2(f[12], f[13]), pack_bf2(f[14], f[15]));
    *(uint4*)(dst + idx) = o0;
    *(uint4*)(dst + idx + 8) = o1;
}

// ---------------------------------------------------------------------------
// pack_w: WpackT[w*1024 + h*64 + s][d] = W_w[h][d][s]  (fp32 -> bf16, n-major)
// ---------------------------------------------------------------------------
__global__ __launch_bounds__(256) void pack_w(
    const float* __restrict__ Wq, const float* __restrict__ Wk,
    const float* __restrict__ Wv, ushort_t* __restrict__ WpT)
{
    __shared__ ushort_t L[64 * 72];
    const int tid = threadIdx.x;
    const int d0 = blockIdx.x * 64;
    const int wh = blockIdx.y;
    const int w = wh >> 4, h = wh & 15;
    const float* W = (w == 0 ? Wq : (w == 1 ? Wk : Wv)) + (size_t)h * DMODEL * HSZ;

    int dr = tid >> 2, sc = (tid & 3) * 16;
    const float4* src = (const float4*)(W + (size_t)(d0 + dr) * HSZ + sc);
    float f[16];
    *(float4*)(f + 0) = src[0]; *(float4*)(f + 4) = src[1];
    *(float4*)(f + 8) = src[2]; *(float4*)(f + 12) = src[3];
    *(short8*)(L + dr * 72 + sc)     = cvt8(f);
    *(short8*)(L + dr * 72 + sc + 8) = cvt8(f + 8);
    __syncthreads();

    int s = tid >> 2, dc = (tid & 3) * 16;
    union { ushort_t u[16]; short8 v[2]; } o;
    #pragma unroll
    for (int j = 0; j < 16; ++j) o.u[j] = L[(dc + j) * 72 + s];
    ushort_t* dst = WpT + (size_t)(w * 1024 + h * 64 + s) * DMODEL + d0 + dc;
    *(short8*)dst = o.v[0];
    *(short8*)(dst + 8) = o.v[1];
}

// ---------------------------------------------------------------------------
// transpose_v: Vt[bh][s][t] = Vb[bh][t][s]   (bf16)
// ---------------------------------------------------------------------------
__global__ __launch_bounds__(256) void transpose_v(
    const ushort_t* __restrict__ Vb, ushort_t* __restrict__ Vt)
{
    __shared__ ushort_t L[64 * 72];
    const int tid = threadIdx.x;
    const int t0 = blockIdx.x * 64;
    const int bh = blockIdx.y;
    const size_t base = (size_t)bh * TSEQ * HSZ;

    int r = tid >> 2, c16 = (tid & 3) * 16;
    const ushort_t* src = Vb + base + (size_t)(t0 + r) * HSZ + c16;
    *(short8*)(L + r * 72 + c16)     = *(const short8*)src;
    *(short8*)(L + r * 72 + c16 + 8) = *(const short8*)(src + 8);
    __syncthreads();

    int s = tid >> 2, tc = (tid & 3) * 16;
    union { ushort_t u[16]; short8 v[2]; } o;
    #pragma unroll
    for (int j = 0; j < 16; ++j) o.u[j] = L[(tc + j) * 72 + s];
    ushort_t* dst = Vt + base + (size_t)s * TSEQ + t0 + tc;
    *(short8*)dst = o.v[0];
    *(short8*)(dst + 8) = o.v[1];
}

// ---------------------------------------------------------------------------
// qkv_gemm: m97-style. Block 128x128, BK=64, SINGLE-buffered As/Bs (32 KB ->
// 3-4 blocks/CU; inter-block wave overlap absorbs the barrier drain, m114).
// Both operands staged via global_load_lds. 128-B LDS rows + 8-chunk XOR
// swizzle ch=(lane&7)^(row&7) -- the R3-proven zero-conflict pattern.
// 1-D grid 1536, XCD swizzle: bid&7 selects n-group so each XCD keeps 3 WpT
// slices (~0.75 MB) L2-resident. Q pre-scaled by 0.125*log2(e).
// ---------------------------------------------------------------------------
__global__ __launch_bounds__(256) void qkv_gemm(
    const ushort_t* __restrict__ Xb, const ushort_t* __restrict__ WpT,
    ushort_t* __restrict__ Qb, ushort_t* __restrict__ Kb, ushort_t* __restrict__ Vb)
{
    __shared__ ushort_t As[128 * 64];
    __shared__ ushort_t Bs[128 * 64];
    const int tid = threadIdx.x;
    const int wave = tid >> 6, lane = tid & 63;
    const int q = lane >> 4, cc = lane & 15;
    const int bid = blockIdx.x;
    // decode: bid = (n&7) + 8*(m + 64*(n>>3))
    const int n_blk = (bid & 7) + 8 * (bid >> 9);
    const int m_blk = (bid >> 3) & 63;
    const int n0 = n_blk * 128, m0 = m_blk * 128;
    const int wm = wave >> 1, wn = wave & 1;

    // DMA: 4 A + 4 B instrs per wave, 8 rows each
    const ushort_t* ag[4]; const ushort_t* bg[4]; int lo_[4];
    #pragma unroll
    for (int i = 0; i < 4; ++i) {
        int row = wave * 32 + i * 8 + (lane >> 3);
        int ch = (lane & 7) ^ (row & 7);
        ag[i] = Xb + (size_t)(m0 + row) * DMODEL + ch * 8;
        bg[i] = WpT + (size_t)(n0 + row) * DMODEL + ch * 8;
        lo_[i] = (wave * 32 + i * 8) * 64;
    }
    // fragment offsets (8 chunks per 128-B row, XOR row&7)
    int aoff[4][2], boff[4][2];
    #pragma unroll
    for (int mt = 0; mt < 4; ++mt) {
        int row = wm * 64 + mt * 16 + cc;
        #pragma unroll
        for (int kt = 0; kt < 2; ++kt)
            aoff[mt][kt] = row * 64 + (((kt * 4 + q) ^ (row & 7)) * 8);
    }
    #pragma unroll
    for (int nt = 0; nt < 4; ++nt) {
        int row = wn * 64 + nt * 16 + cc;
        #pragma unroll
        for (int kt = 0; kt < 2; ++kt)
            boff[nt][kt] = row * 64 + (((kt * 4 + q) ^ (row & 7)) * 8);
    }

    float4v acc[4][4];
    #pragma unroll
    for (int a = 0; a < 4; ++a)
        #pragma unroll
        for (int b = 0; b < 4; ++b) acc[a][b] = (float4v){0.f, 0.f, 0.f, 0.f};

    for (int j = 0; j < 16; ++j) {
        #pragma unroll
        for (int i = 0; i < 4; ++i) {
            async16(ag[i], As + lo_[i]);
            async16(bg[i], Bs + lo_[i]);
            ag[i] += 64; bg[i] += 64;
        }
        __syncthreads();   // drain DMA(j); other resident blocks cover the stall

        short8 av[4][2], bv[4][2];
        #pragma unroll
        for (int mt = 0; mt < 4; ++mt) {
            av[mt][0] = *(const short8*)(As + aoff[mt][0]);
            av[mt][1] = *(const short8*)(As + aoff[mt][1]);
        }
        #pragma unroll
        for (int nt = 0; nt < 4; ++nt) {
            bv[nt][0] = *(const short8*)(Bs + boff[nt][0]);
            bv[nt][1] = *(const short8*)(Bs + boff[nt][1]);
        }
        #pragma unroll
        for (int kt = 0; kt < 2; ++kt)
            #pragma unroll
            for (int mt = 0; mt < 4; ++mt)
                #pragma unroll
                for (int nt = 0; nt < 4; ++nt)
                    acc[mt][nt] = __builtin_amdgcn_mfma_f32_16x16x32_bf16(
                        av[mt][kt], bv[nt][kt], acc[mt][nt], 0, 0, 0);
        __syncthreads();   // LDS safe to overwrite next iter
    }

    // epilogue: scatter to Q/K/V [B,H,T,HS]; wsel uniform per wave (n0+wn*64)
    const int nbase = n0 + wn * 64;
    const int wsel = nbase >> 10;
    const int h = (nbase >> 6) & 15;
    ushort_t* Out = wsel == 0 ? Qb : (wsel == 1 ? Kb : Vb);
    const float osc = (wsel == 0) ? 0.18033688011112042f : 1.0f; // 0.125*log2(e)
    #pragma unroll
    for (int mt = 0; mt < 4; ++mt)
        #pragma unroll
        for (int rr = 0; rr < 4; ++rr) {
            int m = m0 + wm * 64 + mt * 16 + q * 4 + rr;
            int b = m >> 10, t = m & 1023;
            size_t rb = (((size_t)(b * NHEAD + h)) * TSEQ + t) * HSZ;
            #pragma unroll
            for (int nt = 0; nt < 4; ++nt)
                Out[rb + nt * 16 + cc] = f2bf_fast(acc[mt][nt][rr] * osc);
        }
}

// ---------------------------------------------------------------------------
// attn: flash attention, Q-tile 128, KV-tile 64, dbuf DMA prefetch, exp2
// softmax without running max. 1-D grid 1024 with bid&7 == bh&7 so all 8
// qt-blocks of a bh land on one XCD -> its 256 KB KV slice is L2-resident.
// ---------------------------------------------------------------------------
__global__ __launch_bounds__(256) void attn(
    const ushort_t* __restrict__ Qb, const ushort_t* __restrict__ Kb,
    const ushort_t* __restrict__ Vt, ushort_t* __restrict__ Ob)
{
    __shared__ ushort_t Ks[2][64 * 64];
    __shared__ ushort_t VTs[2][64 * 64];
    __shared__ ushort_t Ps[4][32 * 72];
    const int tid = threadIdx.x;
    const int wave = tid >> 6, lane = tid & 63;
    const int q = lane >> 4, cc = lane & 15;
    const int bid = blockIdx.x;
    const int qt = 7 - (bid >> 7);    // big-J blocks first
    const int bh = bid & 127;         // bid&7 == bh&7 -> same-bh co-XCD
    const size_t base = (size_t)bh * TSEQ * HSZ;
    const int J = 2 * qt + 2;

    const ushort_t* kg[2]; const ushort_t* vg[2]; int dmo[2];
    #pragma unroll
    for (int i = 0; i < 2; ++i) {
        int rr = wave * 16 + i * 8 + (lane >> 3);
        int ch = (lane & 7) ^ (rr & 7);
        kg[i] = Kb + base + (size_t)rr * HSZ + ch * 8;
        vg[i] = Vt + base + (size_t)rr * TSEQ + ch * 8;
        dmo[i] = (wave * 16 + i * 8) * 64;
    }

    short8 qf[2][2];
    #pragma unroll
    for (int tt = 0; tt < 2; ++tt) {
        const ushort_t* qp = Qb + base +
            (size_t)(qt * 128 + wave * 32 + tt * 16 + cc) * HSZ + q * 8;
        qf[tt][0] = *(const short8*)qp;
        qf[tt][1] = *(const short8*)(qp + 32);
    }

    int koff[4][2], poff[2][2];
    #pragma unroll
    for (int ut = 0; ut < 4; ++ut)
        #pragma unroll
        for (int kt = 0; kt < 2; ++kt)
            koff[ut][kt] = (ut * 16 + cc) * 64 + (((kt * 4 + q) ^ (cc & 7)) * 8);
    #pragma unroll
    for (int tt = 0; tt < 2; ++tt)
        #pragma unroll
        for (int kt = 0; kt < 2; ++kt)
            poff[tt][kt] = (tt * 16 + cc) * 72 + kt * 32 + q * 8;

    float4v oacc[2][4];
    #pragma unroll
    for (int tt = 0; tt < 2; ++tt)
        #pragma unroll
        for (int st = 0; st < 4; ++st) oacc[tt][st] = (float4v){0.f, 0.f, 0.f, 0.f};
    float lsum[2] = {0.f, 0.f};

    #pragma unroll
    for (int i = 0; i < 2; ++i) {
        async16(kg[i], &Ks[0][dmo[i]]);
        async16(vg[i], &VTs[0][dmo[i]]);
    }
    __syncthreads();

    for (int jt = 0; jt < J; ++jt) {
        const ushort_t* Kc = Ks[jt & 1];
        const ushort_t* Vc = VTs[jt & 1];
        if (jt + 1 < J) {
            int nb = (jt + 1) & 1;
            #pragma unroll
            for (int i = 0; i < 2; ++i) {
                async16(kg[i] + (size_t)(jt + 1) * 64 * HSZ, &Ks[nb][dmo[i]]);
                async16(vg[i] + (jt + 1) * 64, &VTs[nb][dmo[i]]);
            }
        }

        float4v sc[4][2];
        #pragma unroll
        for (int ut = 0; ut < 4; ++ut)
            #pragma unroll
            for (int tt = 0; tt < 2; ++tt) sc[ut][tt] = (float4v){0.f, 0.f, 0.f, 0.f};
        #pragma unroll
        for (int kt = 0; kt < 2; ++kt) {
            short8 kf[4];
            #pragma unroll
            for (int ut = 0; ut < 4; ++ut) kf[ut] = *(const short8*)(Kc + koff[ut][kt]);
            #pragma unroll
            for (int ut = 0; ut < 4; ++ut) {
                sc[ut][0] = __builtin_amdgcn_mfma_f32_16x16x32_bf16(
                    kf[ut], qf[0][kt], sc[ut][0], 0, 0, 0);
                sc[ut][1] = __builtin_amdgcn_mfma_f32_16x16x32_bf16(
                    kf[ut], qf[1][kt], sc[ut][1], 0, 0, 0);
            }
        }

        const bool diag = ((jt >> 1) == qt);
        #pragma unroll
        for (int tt = 0; tt < 2; ++tt) {
            const int tg = qt * 128 + wave * 32 + tt * 16 + cc;
            #pragma unroll
            for (int ut = 0; ut < 4; ++ut) {
                float pv[4]; float ps = 0.f;
                #pragma unroll
                for (int rr = 0; rr < 4; ++rr) {
                    float p = exp2f(sc[ut][tt][rr]);
                    if (diag && (jt * 64 + ut * 16 + q * 4 + rr) > tg) p = 0.f;
                    pv[rr] = p; ps += p;
                }
                lsum[tt] += ps;
                *(uint2*)&Ps[wave][(tt * 16 + cc) * 72 + ut * 16 + q * 4] =
                    make_uint2(pack_bf2(pv[0], pv[1]), pack_bf2(pv[2], pv[3]));
            }
        }

        #pragma unroll
        for (int kt = 0; kt < 2; ++kt) {
            short8 pa0 = *(const short8*)&Ps[wave][poff[0][kt]];
            short8 pa1 = *(const short8*)&Ps[wave][poff[1][kt]];
            #pragma unroll
            for (int st = 0; st < 4; ++st) {
                short8 vf = *(const short8*)(Vc + koff[st][kt]);
                oacc[0][st] = __builtin_amdgcn_mfma_f32_16x16x32_bf16(
                    pa0, vf, oacc[0][st], 0, 0, 0);
                oacc[1][st] = __builtin_amdgcn_mfma_f32_16x16x32_bf16(
                    pa1, vf, oacc[1][st], 0, 0, 0);
            }
        }
        __syncthreads();
    }

    float inv[2];
    #pragma unroll
    for (int tt = 0; tt < 2; ++tt) {
        float l = lsum[tt];
        l += __shfl_xor(l, 16);
        l += __shfl_xor(l, 32);
        inv[tt] = 1.f / l;
    }
    const int b = bh >> 4, h = bh & 15;
    #pragma unroll
    for (int tt = 0; tt < 2; ++tt)
        #pragma unroll
        for (int rr = 0; rr < 4; ++rr) {
            float iv = __shfl(inv[tt], q * 4 + rr);
            int t = qt * 128 + wave * 32 + tt * 16 + q * 4 + rr;
            size_t rb = ((size_t)b * TSEQ + t) * DMODEL + h * HSZ;
            #pragma unroll
            for (int st = 0; st < 4; ++st)
                Ob[rb + st * 16 + cc] = f2bf_fast(oacc[tt][st][rr] * iv);
        }
}

// ---------------------------------------------------------------------------
// oproj_gemm: m97-clone of qkv_gemm. out[m][n] = sum_k Ob[m][k]*Wob[n][k]+bo[n].
// Both operands bf16 via DMA (Wob pre-converted into dead Kb region).
// 1-D grid 512: bid&7 = n-slice -> one 256 KB Wo slice per XCD.
// ---------------------------------------------------------------------------
__global__ __launch_bounds__(256) void oproj_gemm(
    const ushort_t* __restrict__ Obuf, const ushort_t* __restrict__ Wob,
    const float* __restrict__ bo, float* __restrict__ out)
{
    __shared__ ushort_t As[128 * 64];
    __shared__ ushort_t Bs[128 * 64];
    const int tid = threadIdx.x;
    const int wave = tid >> 6, lane = tid & 63;
    const int q = lane >> 4, cc = lane & 15;
    const int bid = blockIdx.x;
    const int n0 = (bid & 7) * 128, m0 = (bid >> 3) * 128;
    const int wm = wave >> 1, wn = wave & 1;

    const ushort_t* ag[4]; const ushort_t* bg[4]; int lo_[4];
    #pragma unroll
    for (int i = 0; i < 4; ++i) {
        int row = wave * 32 + i * 8 + (lane >> 3);
        int ch = (lane & 7) ^ (row & 7);
        ag[i] = Obuf + (size_t)(m0 + row) * DMODEL + ch * 8;
        bg[i] = Wob + (size_t)(n0 + row) * DMODEL + ch * 8;
        lo_[i] = (wave * 32 + i * 8) * 64;
    }
    int aoff[4][2], boff[4][2];
    #pragma unroll
    for (int mt = 0; mt < 4; ++mt) {
        int row = wm * 64 + mt * 16 + cc;
        #pragma unroll
        for (int kt = 0; kt < 2; ++kt)
            aoff[mt][kt] = row * 64 + (((kt * 4 + q) ^ (row & 7)) * 8);
    }
    #pragma unroll
    for (int nt = 0; nt < 4; ++nt) {
        int row = wn * 64 + nt * 16 + cc;
        #pragma unroll
        for (int kt = 0; kt < 2; ++kt)
            boff[nt][kt] = row * 64 + (((kt * 4 + q) ^ (row & 7)) * 8);
    }

    float4v acc[4][4];
    #pragma unroll
    for (int a = 0; a < 4; ++a)
        #pragma unroll
        for (int b = 0; b < 4; ++b) acc[a][b] = (float4v){0.f, 0.f, 0.f, 0.f};

    for (int j = 0; j < 16; ++j) {
        #pragma unroll
        for (int i = 0; i < 4; ++i) {
            async16(ag[i], As + lo_[i]);
            async16(bg[i], Bs + lo_[i]);
            ag[i] += 64; bg[i] += 64;
        }
        __syncthreads();

        short8 av[4][2], bv[4][2];
        #pragma unroll
        for (int mt = 0; mt < 4; ++mt) {
            av[mt][0] = *(const short8*)(As + aoff[mt][0]);
            av[mt][1] = *(const short8*)(As + aoff[mt][1]);
        }
        #pragma unroll
        for (int nt = 0; nt < 4; ++nt) {
            bv[nt][0] = *(const short8*)(Bs + boff[nt][0]);
            bv[nt][1] = *(const short8*)(Bs + boff[nt][1]);
        }
        #pragma unroll
        for (int kt = 0; kt < 2; ++kt)
            #pragma unroll
            for (int mt = 0; mt < 4; ++mt)
                #pragma unroll
                for (int nt = 0; nt < 4; ++nt)
                    acc[mt][nt] = __builtin_amdgcn_mfma_f32_16x16x32_bf16(
                        av[mt][kt], bv[nt][kt], acc[mt][nt], 0, 0, 0);
        __syncthreads();
    }

    #pragma unroll
    for (int nt = 0; nt < 4; ++nt) {
        int n = n0 + wn * 64 + nt * 16 + cc;
        float bias = bo[n];
        #pragma unroll
        for (int mt = 0; mt < 4; ++mt)
            #pragma unroll
            for (int rr = 0; rr < 4; ++rr) {
                int m = m0 + wm * 64 + mt * 16 + q * 4 + rr;
                out[(size_t)m * DMODEL + n] = acc[mt][nt][rr] + bias;
            }
    }
}

// ---------------------------------------------------------------------------
extern "C" void kernel_launch(void* const* d_in, const int* in_sizes, int n_in,
                              void* d_out, int out_size, void* d_ws, size_t ws_size,
                              hipStream_t stream)
{
    const float* x  = (const float*)d_in[0];
    const float* Wq = (const float*)d_in[1];
    const float* Wk = (const float*)d_in[2];
    const float* Wv = (const float*)d_in[3];
    const float* Wo = (const float*)d_in[4];
    const float* bo = (const float*)d_in[5];
    float* out = (float*)d_out;

    // ws (64MB): [0,16M) Qb  [16,32) Kb (->Wob after attn)  [32,48) Vb->Ob
    //            [48,64) WpT->Vt
    // Xb (bf16 X, 16MB) in d_out's first half (dead before oproj writes out).
    const size_t SEG = (size_t)8 * 1024 * 1024;
    ushort_t* Qb  = (ushort_t*)d_ws;
    ushort_t* Kb  = Qb + SEG;
    ushort_t* Vb  = Kb + SEG;
    ushort_t* Ob  = Vb;          // Vb dead after transpose_v
    ushort_t* WpT = Vb + SEG;
    ushort_t* Vtb = WpT;         // WpT dead after qkv_gemm
    ushort_t* Xb  = (ushort_t*)d_out;
    ushort_t* Wob = Kb;          // Kb dead after attn

    cvt_f32_bf16<<<dim3(2048),    256, 0, stream>>>(x, Xb);
    pack_w      <<<dim3(16, 48),  256, 0, stream>>>(Wq, Wk, Wv, WpT);
    qkv_gemm    <<<dim3(1536),    256, 0, stream>>>(Xb, WpT, Qb, Kb, Vb);
    transpose_v <<<dim3(16, 128), 256, 0, stream>>>(Vb, Vtb);
    attn        <<<dim3(1024),    256, 0, stream>>>(Qb, Kb, Vtb, Ob);
    cvt_f32_bf16<<<dim3(256),     256, 0, stream>>>(Wo, Wob);
    oproj_gemm  <<<dim3(512),     256, 0, stream>>>(Ob, Wob, bo, out);
}

// Round 7
// 230.691 us; speedup vs baseline: 1.2695x; 1.0724x over previous
//
#include <hip/hip_runtime.h>
#include <hip/hip_bf16.h>

#define BBATCH 8
#define TSEQ   1024
#define DMODEL 1024
#define NHEAD  16
#define HSZ    64

typedef unsigned short ushort_t;
typedef __attribute__((ext_vector_type(8))) short short8;
typedef __attribute__((ext_vector_type(4))) float float4v;

__device__ __forceinline__ ushort_t f2bf(float f) {
    __hip_bfloat16 h = __float2bfloat16(f);
    return *reinterpret_cast<ushort_t*>(&h);
}
// fast fp32->bf16, round-half-up
__device__ __forceinline__ ushort_t f2bf_fast(float f) {
    return (ushort_t)((__float_as_uint(f) + 0x8000u) >> 16);
}
// pack two fp32 -> uint {bf16(lo), bf16(hi)}
__device__ __forceinline__ unsigned int pack_bf2(float lo, float hi) {
    unsigned int a = __float_as_uint(lo) + 0x8000u;
    unsigned int b = __float_as_uint(hi) + 0x8000u;
    return __builtin_amdgcn_perm(b, a, 0x07060302u);
}

__device__ __forceinline__ short8 cvt8(const float* f) {
    union { ushort_t u[8]; short8 v; } r;
    #pragma unroll
    for (int e = 0; e < 8; ++e) r.u[e] = f2bf(f[e]);
    return r.v;
}

// async global->LDS, 16B/lane; lds base wave-uniform (HW: base + lane*16)
__device__ __forceinline__ void async16(const ushort_t* g, ushort_t* l) {
    __builtin_amdgcn_global_load_lds(
        (const __attribute__((address_space(1))) unsigned int*)g,
        (__attribute__((address_space(3))) unsigned int*)l, 16, 0, 0);
}

// ---------------------------------------------------------------------------
// cvt_f32_bf16: generic fp32 -> bf16, 16 elems/thread (X, Wo)
// ---------------------------------------------------------------------------
__global__ __launch_bounds__(256) void cvt_f32_bf16(
    const float* __restrict__ src, ushort_t* __restrict__ dst)
{
    const size_t idx = ((size_t)blockIdx.x * 256 + threadIdx.x) * 16;
    float f[16];
    *(float4*)(f + 0)  = *(const float4*)(src + idx);
    *(float4*)(f + 4)  = *(const float4*)(src + idx + 4);
    *(float4*)(f + 8)  = *(const float4*)(src + idx + 8);
    *(float4*)(f + 12) = *(const float4*)(src + idx + 12);
    uint4 o0 = make_uint4(pack_bf2(f[0], f[1]),   pack_bf2(f[2], f[3]),
                          pack_bf2(f[4], f[5]),   pack_bf2(f[6], f[7]));
    uint4 o1 = make_uint4(pack_bf2(f[8], f[9]),   pack_bf2(f[10], f[11]),
                          pack_bf2(f[12], f[13]), pack_bf2(f[14], f[15]));
    *(uint4*)(dst + idx) = o0;
    *(uint4*)(dst + idx + 8) = o1;
}

// ---------------------------------------------------------------------------
// pack_w: WpackT[w*1024 + h*64 + s][d] = W_w[h][d][s]  (fp32 -> bf16, n-major)
// ---------------------------------------------------------------------------
__global__ __launch_bounds__(256) void pack_w(
    const float* __restrict__ Wq, const float* __restrict__ Wk,
    const float* __restrict__ Wv, ushort_t* __restrict__ WpT)
{
    __shared__ ushort_t L[64 * 72];
    const int tid = threadIdx.x;
    const int d0 = blockIdx.x * 64;
    const int wh = blockIdx.y;
    const int w = wh >> 4, h = wh & 15;
    const float* W = (w == 0 ? Wq : (w == 1 ? Wk : Wv)) + (size_t)h * DMODEL * HSZ;

    int dr = tid >> 2, sc = (tid & 3) * 16;
    const float4* src = (const float4*)(W + (size_t)(d0 + dr) * HSZ + sc);
    float f[16];
    *(float4*)(f + 0) = src[0]; *(float4*)(f + 4) = src[1];
    *(float4*)(f + 8) = src[2]; *(float4*)(f + 12) = src[3];
    *(short8*)(L + dr * 72 + sc)     = cvt8(f);
    *(short8*)(L + dr * 72 + sc + 8) = cvt8(f + 8);
    __syncthreads();

    int s = tid >> 2, dc = (tid & 3) * 16;
    union { ushort_t u[16]; short8 v[2]; } o;
    #pragma unroll
    for (int j = 0; j < 16; ++j) o.u[j] = L[(dc + j) * 72 + s];
    ushort_t* dst = WpT + (size_t)(w * 1024 + h * 64 + s) * DMODEL + d0 + dc;
    *(short8*)dst = o.v[0];
    *(short8*)(dst + 8) = o.v[1];
}

// ---------------------------------------------------------------------------
// qkv_gemm: m97-style 128x128, BK=64, single-buffered LDS, dual DMA staging.
// XCD m-banding: bid&7 ~ XCD; each XCD owns an 8-block m-band (2 MB X,
// L2-resident) and streams all of WpT (6 MB), m fastest.
// Q/K blocks compute C^T = W·X^T (row = s) -> packed 8B stores to [t][s];
// V blocks compute C = X·W^T (row = t) -> packed 8B stores DIRECT to
// Vt[bh][s][t] (transpose fused; transpose_v kernel deleted).
// Q pre-scaled by 0.125*log2(e). grid 1536.
// ---------------------------------------------------------------------------
__global__ __launch_bounds__(256) void qkv_gemm(
    const ushort_t* __restrict__ Xb, const ushort_t* __restrict__ WpT,
    ushort_t* __restrict__ Qb, ushort_t* __restrict__ Kb, ushort_t* __restrict__ Vt)
{
    __shared__ ushort_t As[128 * 64];
    __shared__ ushort_t Bs[128 * 64];
    const int tid = threadIdx.x;
    const int wave = tid >> 6, lane = tid & 63;
    const int q = lane >> 4, cc = lane & 15;
    const int bid = blockIdx.x;
    const int xcd = bid & 7, local = bid >> 3;
    const int n_blk = local >> 3;              // 0..23 (slow: W streams)
    const int m_blk = xcd * 8 + (local & 7);   // m-band per XCD (fast)
    const int n0 = n_blk * 128, m0 = m_blk * 128;
    const int wm = wave >> 1, wn = wave & 1;
    const bool isV = (n0 >= 2048);

    // DMA: 4 A + 4 B instrs per wave, 8 rows each; XOR-8 swizzle in source col
    const ushort_t* ag[4]; const ushort_t* bg[4]; int lo_[4];
    #pragma unroll
    for (int i = 0; i < 4; ++i) {
        int row = wave * 32 + i * 8 + (lane >> 3);
        int ch = (lane & 7) ^ (row & 7);
        ag[i] = Xb + (size_t)(m0 + row) * DMODEL + ch * 8;
        bg[i] = WpT + (size_t)(n0 + row) * DMODEL + ch * 8;
        lo_[i] = (wave * 32 + i * 8) * 64;
    }
    int aoff[4][2], boff[4][2];
    #pragma unroll
    for (int mt = 0; mt < 4; ++mt) {
        int row = wm * 64 + mt * 16 + cc;
        #pragma unroll
        for (int kt = 0; kt < 2; ++kt)
            aoff[mt][kt] = row * 64 + (((kt * 4 + q) ^ (row & 7)) * 8);
    }
    #pragma unroll
    for (int nt = 0; nt < 4; ++nt) {
        int row = wn * 64 + nt * 16 + cc;
        #pragma unroll
        for (int kt = 0; kt < 2; ++kt)
            boff[nt][kt] = row * 64 + (((kt * 4 + q) ^ (row & 7)) * 8);
    }

    float4v acc[4][4];
    #pragma unroll
    for (int a = 0; a < 4; ++a)
        #pragma unroll
        for (int b = 0; b < 4; ++b) acc[a][b] = (float4v){0.f, 0.f, 0.f, 0.f};

    for (int j = 0; j < 16; ++j) {
        #pragma unroll
        for (int i = 0; i < 4; ++i) {
            async16(ag[i], As + lo_[i]);
            async16(bg[i], Bs + lo_[i]);
            ag[i] += 64; bg[i] += 64;
        }
        __syncthreads();   // drain DMA(j); co-resident blocks cover the stall

        short8 av[4][2], bv[4][2];
        #pragma unroll
        for (int mt = 0; mt < 4; ++mt) {
            av[mt][0] = *(const short8*)(As + aoff[mt][0]);
            av[mt][1] = *(const short8*)(As + aoff[mt][1]);
        }
        #pragma unroll
        for (int nt = 0; nt < 4; ++nt) {
            bv[nt][0] = *(const short8*)(Bs + boff[nt][0]);
            bv[nt][1] = *(const short8*)(Bs + boff[nt][1]);
        }
        if (isV) {
            #pragma unroll
            for (int kt = 0; kt < 2; ++kt)
                #pragma unroll
                for (int mt = 0; mt < 4; ++mt)
                    #pragma unroll
                    for (int nt = 0; nt < 4; ++nt)
                        acc[mt][nt] = __builtin_amdgcn_mfma_f32_16x16x32_bf16(
                            av[mt][kt], bv[nt][kt], acc[mt][nt], 0, 0, 0);
        } else {
            #pragma unroll
            for (int kt = 0; kt < 2; ++kt)
                #pragma unroll
                for (int nt = 0; nt < 4; ++nt)
                    #pragma unroll
                    for (int mt = 0; mt < 4; ++mt)
                        acc[nt][mt] = __builtin_amdgcn_mfma_f32_16x16x32_bf16(
                            bv[nt][kt], av[mt][kt], acc[nt][mt], 0, 0, 0);
        }
        __syncthreads();
    }

    if (isV) {
        // acc[mt][nt]: row = t (q*4+rr contiguous), col = s (cc).
        // Write Vt[(b*16+h)][s][t0..t0+4): one 8B store per (mt,nt).
        #pragma unroll
        for (int mt = 0; mt < 4; ++mt) {
            int m = m0 + wm * 64 + mt * 16 + q * 4;
            int b = m >> 10, t0_ = m & 1023;
            #pragma unroll
            for (int nt = 0; nt < 4; ++nt) {
                int n = n0 + wn * 64 + nt * 16 + cc;
                int h = (n >> 6) & 15, s = n & 63;
                size_t addr = (((size_t)(b * NHEAD + h)) * HSZ + s) * TSEQ + t0_;
                uint2 pk = make_uint2(pack_bf2(acc[mt][nt][0], acc[mt][nt][1]),
                                      pack_bf2(acc[mt][nt][2], acc[mt][nt][3]));
                *(uint2*)(Vt + addr) = pk;
            }
        }
    } else {
        // acc[nt][mt]: row = s (q*4+rr contiguous), col = t (cc).
        const int nbase = n0 + wn * 64;
        ushort_t* Out = (nbase < 1024) ? Qb : Kb;
        const float osc = (nbase < 1024) ? 0.18033688011112042f : 1.0f;
        #pragma unroll
        for (int mt = 0; mt < 4; ++mt) {
            int m = m0 + wm * 64 + mt * 16 + cc;
            int b = m >> 10, t_ = m & 1023;
            #pragma unroll
            for (int nt = 0; nt < 4; ++nt) {
                int n = nbase + nt * 16 + q * 4;
                int h = (n >> 6) & 15, s0 = n & 63;
                size_t addr = (((size_t)(b * NHEAD + h)) * TSEQ + t_) * HSZ + s0;
                uint2 pk = make_uint2(
                    pack_bf2(acc[nt][mt][0] * osc, acc[nt][mt][1] * osc),
                    pack_bf2(acc[nt][mt][2] * osc, acc[nt][mt][3] * osc));
                *(uint2*)(Out + addr) = pk;
            }
        }
    }
}

// ---------------------------------------------------------------------------
// attn: flash attention, Q-tile 128, KV-tile 64, dbuf DMA prefetch, exp2
// softmax without running max; causal mask only on the 2 diagonal jt-tiles
// (wave-uniform branch). 1-D grid 1024, bid&7 == bh&7 -> per-bh KV co-XCD.
// ---------------------------------------------------------------------------
__global__ __launch_bounds__(256) void attn(
    const ushort_t* __restrict__ Qb, const ushort_t* __restrict__ Kb,
    const ushort_t* __restrict__ Vt, ushort_t* __restrict__ Ob)
{
    __shared__ ushort_t Ks[2][64 * 64];
    __shared__ ushort_t VTs[2][64 * 64];
    __shared__ ushort_t Ps[4][32 * 72];
    const int tid = threadIdx.x;
    const int wave = tid >> 6, lane = tid & 63;
    const int q = lane >> 4, cc = lane & 15;
    const int bid = blockIdx.x;
    const int qt = 7 - (bid >> 7);    // big-J blocks first
    const int bh = bid & 127;
    const size_t base = (size_t)bh * TSEQ * HSZ;
    const int J = 2 * qt + 2;

    const ushort_t* kg[2]; const ushort_t* vg[2]; int dmo[2];
    #pragma unroll
    for (int i = 0; i < 2; ++i) {
        int rr = wave * 16 + i * 8 + (lane >> 3);
        int ch = (lane & 7) ^ (rr & 7);
        kg[i] = Kb + base + (size_t)rr * HSZ + ch * 8;
        vg[i] = Vt + base + (size_t)rr * TSEQ + ch * 8;
        dmo[i] = (wave * 16 + i * 8) * 64;
    }

    short8 qf[2][2];
    #pragma unroll
    for (int tt = 0; tt < 2; ++tt) {
        const ushort_t* qp = Qb + base +
            (size_t)(qt * 128 + wave * 32 + tt * 16 + cc) * HSZ + q * 8;
        qf[tt][0] = *(const short8*)qp;
        qf[tt][1] = *(const short8*)(qp + 32);
    }

    int koff[4][2], poff[2][2];
    #pragma unroll
    for (int ut = 0; ut < 4; ++ut)
        #pragma unroll
        for (int kt = 0; kt < 2; ++kt)
            koff[ut][kt] = (ut * 16 + cc) * 64 + (((kt * 4 + q) ^ (cc & 7)) * 8);
    #pragma unroll
    for (int tt = 0; tt < 2; ++tt)
        #pragma unroll
        for (int kt = 0; kt < 2; ++kt)
            poff[tt][kt] = (tt * 16 + cc) * 72 + kt * 32 + q * 8;

    float4v oacc[2][4];
    #pragma unroll
    for (int tt = 0; tt < 2; ++tt)
        #pragma unroll
        for (int st = 0; st < 4; ++st) oacc[tt][st] = (float4v){0.f, 0.f, 0.f, 0.f};
    float lsum[2] = {0.f, 0.f};

    #pragma unroll
    for (int i = 0; i < 2; ++i) {
        async16(kg[i], &Ks[0][dmo[i]]);
        async16(vg[i], &VTs[0][dmo[i]]);
    }
    __syncthreads();

    for (int jt = 0; jt < J; ++jt) {
        const ushort_t* Kc = Ks[jt & 1];
        const ushort_t* Vc = VTs[jt & 1];
        if (jt + 1 < J) {
            int nb = (jt + 1) & 1;
            #pragma unroll
            for (int i = 0; i < 2; ++i) {
                async16(kg[i] + (size_t)(jt + 1) * 64 * HSZ, &Ks[nb][dmo[i]]);
                async16(vg[i] + (jt + 1) * 64, &VTs[nb][dmo[i]]);
            }
        }

        float4v sc[4][2];
        #pragma unroll
        for (int ut = 0; ut < 4; ++ut)
            #pragma unroll
            for (int tt = 0; tt < 2; ++tt) sc[ut][tt] = (float4v){0.f, 0.f, 0.f, 0.f};
        #pragma unroll
        for (int kt = 0; kt < 2; ++kt) {
            short8 kf[4];
            #pragma unroll
            for (int ut = 0; ut < 4; ++ut) kf[ut] = *(const short8*)(Kc + koff[ut][kt]);
            #pragma unroll
            for (int ut = 0; ut < 4; ++ut) {
                sc[ut][0] = __builtin_amdgcn_mfma_f32_16x16x32_bf16(
                    kf[ut], qf[0][kt], sc[ut][0], 0, 0, 0);
                sc[ut][1] = __builtin_amdgcn_mfma_f32_16x16x32_bf16(
                    kf[ut], qf[1][kt], sc[ut][1], 0, 0, 0);
            }
        }

        if ((jt >> 1) == qt) {   // diagonal tiles: masked path
            #pragma unroll
            for (int tt = 0; tt < 2; ++tt) {
                const int tg = qt * 128 + wave * 32 + tt * 16 + cc;
                #pragma unroll
                for (int ut = 0; ut < 4; ++ut) {
                    float pv[4]; float ps = 0.f;
                    #pragma unroll
                    for (int rr = 0; rr < 4; ++rr) {
                        float p = exp2f(sc[ut][tt][rr]);
                        if ((jt * 64 + ut * 16 + q * 4 + rr) > tg) p = 0.f;
                        pv[rr] = p; ps += p;
                    }
                    lsum[tt] += ps;
                    *(uint2*)&Ps[wave][(tt * 16 + cc) * 72 + ut * 16 + q * 4] =
                        make_uint2(pack_bf2(pv[0], pv[1]), pack_bf2(pv[2], pv[3]));
                }
            }
        } else {                 // interior tiles: no mask
            #pragma unroll
            for (int tt = 0; tt < 2; ++tt) {
                #pragma unroll
                for (int ut = 0; ut < 4; ++ut) {
                    float pv[4]; float ps = 0.f;
                    #pragma unroll
                    for (int rr = 0; rr < 4; ++rr) {
                        float p = exp2f(sc[ut][tt][rr]);
                        pv[rr] = p; ps += p;
                    }
                    lsum[tt] += ps;
                    *(uint2*)&Ps[wave][(tt * 16 + cc) * 72 + ut * 16 + q * 4] =
                        make_uint2(pack_bf2(pv[0], pv[1]), pack_bf2(pv[2], pv[3]));
                }
            }
        }

        #pragma unroll
        for (int kt = 0; kt < 2; ++kt) {
            short8 pa0 = *(const short8*)&Ps[wave][poff[0][kt]];
            short8 pa1 = *(const short8*)&Ps[wave][poff[1][kt]];
            #pragma unroll
            for (int st = 0; st < 4; ++st) {
                short8 vf = *(const short8*)(Vc + koff[st][kt]);
                oacc[0][st] = __builtin_amdgcn_mfma_f32_16x16x32_bf16(
                    pa0, vf, oacc[0][st], 0, 0, 0);
                oacc[1][st] = __builtin_amdgcn_mfma_f32_16x16x32_bf16(
                    pa1, vf, oacc[1][st], 0, 0, 0);
            }
        }
        __syncthreads();
    }

    float inv[2];
    #pragma unroll
    for (int tt = 0; tt < 2; ++tt) {
        float l = lsum[tt];
        l += __shfl_xor(l, 16);
        l += __shfl_xor(l, 32);
        inv[tt] = 1.f / l;
    }
    const int b = bh >> 4, h = bh & 15;
    #pragma unroll
    for (int tt = 0; tt < 2; ++tt)
        #pragma unroll
        for (int rr = 0; rr < 4; ++rr) {
            float iv = __shfl(inv[tt], q * 4 + rr);
            int t = qt * 128 + wave * 32 + tt * 16 + q * 4 + rr;
            size_t rb = ((size_t)b * TSEQ + t) * DMODEL + h * HSZ;
            #pragma unroll
            for (int st = 0; st < 4; ++st)
                Ob[rb + st * 16 + cc] = f2bf_fast(oacc[tt][st][rr] * iv);
        }
}

// ---------------------------------------------------------------------------
// oproj_gemm: out[m][n] = sum_k Ob[m][k]*Wob[n][k] + bo[n]. m97 structure.
// XCD m-banding: per-XCD 8 m-blocks (2 MB Ob) + Wob 2 MB -> 4 MB, L2-resident.
// grid 512.
// ---------------------------------------------------------------------------
__global__ __launch_bounds__(256) void oproj_gemm(
    const ushort_t* __restrict__ Obuf, const ushort_t* __restrict__ Wob,
    const float* __restrict__ bo, float* __restrict__ out)
{
    __shared__ ushort_t As[128 * 64];
    __shared__ ushort_t Bs[128 * 64];
    const int tid = threadIdx.x;
    const int wave = tid >> 6, lane = tid & 63;
    const int q = lane >> 4, cc = lane & 15;
    const int bid = blockIdx.x;
    const int xcd = bid & 7, local = bid >> 3;
    const int n0 = (local >> 3) * 128;
    const int m0 = (xcd * 8 + (local & 7)) * 128;
    const int wm = wave >> 1, wn = wave & 1;

    const ushort_t* ag[4]; const ushort_t* bg[4]; int lo_[4];
    #pragma unroll
    for (int i = 0; i < 4; ++i) {
        int row = wave * 32 + i * 8 + (lane >> 3);
        int ch = (lane & 7) ^ (row & 7);
        ag[i] = Obuf + (size_t)(m0 + row) * DMODEL + ch * 8;
        bg[i] = Wob + (size_t)(n0 + row) * DMODEL + ch * 8;
        lo_[i] = (wave * 32 + i * 8) * 64;
    }
    int aoff[4][2], boff[4][2];
    #pragma unroll
    for (int mt = 0; mt < 4; ++mt) {
        int row = wm * 64 + mt * 16 + cc;
        #pragma unroll
        for (int kt = 0; kt < 2; ++kt)
            aoff[mt][kt] = row * 64 + (((kt * 4 + q) ^ (row & 7)) * 8);
    }
    #pragma unroll
    for (int nt = 0; nt < 4; ++nt) {
        int row = wn * 64 + nt * 16 + cc;
        #pragma unroll
        for (int kt = 0; kt < 2; ++kt)
            boff[nt][kt] = row * 64 + (((kt * 4 + q) ^ (row & 7)) * 8);
    }

    float4v acc[4][4];
    #pragma unroll
    for (int a = 0; a < 4; ++a)
        #pragma unroll
        for (int b = 0; b < 4; ++b) acc[a][b] = (float4v){0.f, 0.f, 0.f, 0.f};

    for (int j = 0; j < 16; ++j) {
        #pragma unroll
        for (int i = 0; i < 4; ++i) {
            async16(ag[i], As + lo_[i]);
            async16(bg[i], Bs + lo_[i]);
            ag[i] += 64; bg[i] += 64;
        }
        __syncthreads();

        short8 av[4][2], bv[4][2];
        #pragma unroll
        for (int mt = 0; mt < 4; ++mt) {
            av[mt][0] = *(const short8*)(As + aoff[mt][0]);
            av[mt][1] = *(const short8*)(As + aoff[mt][1]);
        }
        #pragma unroll
        for (int nt = 0; nt < 4; ++nt) {
            bv[nt][0] = *(const short8*)(Bs + boff[nt][0]);
            bv[nt][1] = *(const short8*)(Bs + boff[nt][1]);
        }
        #pragma unroll
        for (int kt = 0; kt < 2; ++kt)
            #pragma unroll
            for (int mt = 0; mt < 4; ++mt)
                #pragma unroll
                for (int nt = 0; nt < 4; ++nt)
                    acc[mt][nt] = __builtin_amdgcn_mfma_f32_16x16x32_bf16(
                        av[mt][kt], bv[nt][kt], acc[mt][nt], 0, 0, 0);
        __syncthreads();
    }

    #pragma unroll
    for (int nt = 0; nt < 4; ++nt) {
        int n = n0 + wn * 64 + nt * 16 + cc;
        float bias = bo[n];
        #pragma unroll
        for (int mt = 0; mt < 4; ++mt)
            #pragma unroll
            for (int rr = 0; rr < 4; ++rr) {
                int m = m0 + wm * 64 + mt * 16 + q * 4 + rr;
                out[(size_t)m * DMODEL + n] = acc[mt][nt][rr] + bias;
            }
    }
}

// ---------------------------------------------------------------------------
extern "C" void kernel_launch(void* const* d_in, const int* in_sizes, int n_in,
                              void* d_out, int out_size, void* d_ws, size_t ws_size,
                              hipStream_t stream)
{
    const float* x  = (const float*)d_in[0];
    const float* Wq = (const float*)d_in[1];
    const float* Wk = (const float*)d_in[2];
    const float* Wv = (const float*)d_in[3];
    const float* Wo = (const float*)d_in[4];
    const float* bo = (const float*)d_in[5];
    float* out = (float*)d_out;

    // ws (64MB): [0,16M) Qb (->Wob after attn)  [16,32) Kb  [32,48) Vt
    //            [48,64) WpT (first 6MB, dead after qkv) -> Ob (attn output)
    // Xb (bf16 X, 16MB) in d_out's first half (dead before oproj writes out).
    const size_t SEG = (size_t)8 * 1024 * 1024;
    ushort_t* Qb  = (ushort_t*)d_ws;
    ushort_t* Kb  = Qb + SEG;
    ushort_t* Vtb = Kb + SEG;
    ushort_t* WpT = Vtb + SEG;
    ushort_t* Ob  = WpT;         // WpT dead after qkv_gemm
    ushort_t* Xb  = (ushort_t*)d_out;
    ushort_t* Wob = Qb;          // Qb dead after attn

    cvt_f32_bf16<<<dim3(2048),    256, 0, stream>>>(x, Xb);
    pack_w      <<<dim3(16, 48),  256, 0, stream>>>(Wq, Wk, Wv, WpT);
    qkv_gemm    <<<dim3(1536),    256, 0, stream>>>(Xb, WpT, Qb, Kb, Vtb);
    attn        <<<dim3(1024),    256, 0, stream>>>(Qb, Kb, Vtb, Ob);
    cvt_f32_bf16<<<dim3(256),     256, 0, stream>>>(Wo, Wob);
    oproj_gemm  <<<dim3(512),     256, 0, stream>>>(Ob, Wob, bo, out);
}